// Round 8
// baseline (150.930 us; speedup 1.0000x reference)
//
#include <hip/hip_runtime.h>
#include <hip/hip_bf16.h>

#define S 4096
#define DMODEL 1024
#define DK 128
#define NB_ATTN 1056   // 64-row q-tiles t=0..63, 128-key chunks: sum ceil((t+1)/2)

typedef __attribute__((ext_vector_type(8))) short  short8;   // 8 x bf16 (4 VGPRs)
typedef __attribute__((ext_vector_type(4))) float  f32x4;    // MFMA accumulator
typedef __attribute__((ext_vector_type(4))) unsigned short u16x4;  // 8B pack

__device__ __forceinline__ unsigned short f2bf(float f) {
    return __builtin_bit_cast(unsigned short, __float2bfloat16(f));
}

__device__ __forceinline__ short8 cvt8(float4 a, float4 b) {
    short8 v;
    v[0] = (short)f2bf(a.x); v[1] = (short)f2bf(a.y);
    v[2] = (short)f2bf(a.z); v[3] = (short)f2bf(a.w);
    v[4] = (short)f2bf(b.x); v[5] = (short)f2bf(b.y);
    v[6] = (short)f2bf(b.z); v[7] = (short)f2bf(b.w);
    return v;
}

// ---------------------------------------------------------------------------
// Convert X [S][DMODEL] f32 -> Xb bf16; Wq|Wk|Wv [DK][DMODEL] f32 -> Wb bf16.
// ---------------------------------------------------------------------------
__global__ __launch_bounds__(256) void cvt_kernel(
    const float* __restrict__ X,
    const float* __restrict__ Wq, const float* __restrict__ Wk,
    const float* __restrict__ Wv,
    unsigned short* __restrict__ Xb, unsigned short* __restrict__ Wb)
{
    const int i = blockIdx.x * 256 + threadIdx.x;
    const float* __restrict__ src;
    unsigned short* __restrict__ dst;
    size_t off;
    if (i < 524288) {
        src = X; dst = Xb; off = (size_t)i * 8;
    } else {
        const int j   = i - 524288;
        const int sel = j >> 14, jj = j & 16383;
        src = sel == 0 ? Wq : sel == 1 ? Wk : Wv;
        dst = Wb + (size_t)sel * DK * DMODEL;
        off = (size_t)jj * 8;
    }
    const float4 a = *(const float4*)(src + off);
    const float4 b = *(const float4*)(src + off + 4);
    *(short8*)(dst + off) = cvt8(a, b);
}

// ---------------------------------------------------------------------------
// QKV projection GEMM, bf16. grid = (S/16, 3, 2), block = 128 (2 waves).
// Wave: 16 rows x 32 cols; sel==2 (V) writes DIRECTLY TRANSPOSED to Vt.
// ---------------------------------------------------------------------------
__global__ __launch_bounds__(128) void proj_gemm(
    const unsigned short* __restrict__ Xb, const unsigned short* __restrict__ Wb,
    const float* __restrict__ bq, const float* __restrict__ bk,
    const float* __restrict__ bv,
    unsigned short* __restrict__ Qb, unsigned short* __restrict__ Kb,
    unsigned short* __restrict__ Vt)
{
    const int sel = blockIdx.y;
    const float* __restrict__ bias = sel == 0 ? bq : sel == 1 ? bk : bv;
    const unsigned short* __restrict__ wbase = Wb + (size_t)sel * DK * DMODEL;

    const int tid = threadIdx.x, w = tid >> 6, lane = tid & 63;
    const int li = lane & 15, gl = lane >> 4;
    const int r0 = blockIdx.x * 16;
    const int n0 = blockIdx.z * 64 + w * 32;

    f32x4 acc[2];
    #pragma unroll
    for (int j = 0; j < 2; ++j)
        #pragma unroll
        for (int r = 0; r < 4; ++r) acc[j][r] = 0.f;

    const unsigned short* ap  = &Xb[(size_t)(r0 + li) * DMODEL + 8 * gl];
    const unsigned short* bp0 = &wbase[(size_t)(n0 + li) * DMODEL + 8 * gl];
    const unsigned short* bp1 = bp0 + (size_t)16 * DMODEL;

    #pragma unroll 4
    for (int k0 = 0; k0 < DMODEL; k0 += 32) {
        const short8 a  = *(const short8*)(ap + k0);
        const short8 b0 = *(const short8*)(bp0 + k0);
        const short8 b1 = *(const short8*)(bp1 + k0);
        acc[0] = __builtin_amdgcn_mfma_f32_16x16x32_bf16(a, b0, acc[0], 0, 0, 0);
        acc[1] = __builtin_amdgcn_mfma_f32_16x16x32_bf16(a, b1, acc[1], 0, 0, 0);
    }

    if (sel < 2) {
        unsigned short* __restrict__ Out = sel == 0 ? Qb : Kb;
        #pragma unroll
        for (int j = 0; j < 2; ++j)
            #pragma unroll
            for (int r = 0; r < 4; ++r) {
                const int row = r0 + 4 * gl + r;
                const int col = n0 + 16 * j + li;
                Out[(size_t)row * DK + col] = f2bf(acc[j][r] + bias[col]);
            }
    } else {
        #pragma unroll
        for (int j = 0; j < 2; ++j) {
            const int col = n0 + 16 * j + li;          // dv
            const float bb = bias[col];
            u16x4 wv;
            #pragma unroll
            for (int r = 0; r < 4; ++r) wv[r] = f2bf(acc[j][r] + bb);
            *(u16x4*)&Vt[(size_t)col * S + r0 + 4 * gl] = wv;  // rows 4gl..4gl+3
        }
    }
}

// ---------------------------------------------------------------------------
// Flash attention, bf16 MFMA, swapped QK^T, 2-wave blocks, XOR-SWIZZLED
// LDS K/V tiles (T2: conflict-free ds_read_b128).
// Block = 128 thr = 2 waves; owns 64 q-rows (wave w: 64t+32w..+31) x one
// 128-key chunk. Tile t has ceil((t+1)/2) chunks -> 1056 blocks (4.125/CU,
// LDS 37.9KB -> 4 resident). Per 32-key iter: K 32x128 + V 128x32 staged
// to LDS (reg-staged: loads early, ds_write late, one barrier), shared by
// both waves. Swizzle (identical involution on store & read):
//   K: 16B-chunk ck' = ck ^ (key&7)   (256B rows -> was 16-way conflict)
//   V: 16B-chunk ck' = ck ^ ((dv>>1)&3) (64B rows -> was 8-way conflict)
// Inner math identical to verified round-6/7 kernel.
// ---------------------------------------------------------------------------
__global__ __launch_bounds__(128) void attn_mfma(
    const unsigned short* __restrict__ Qb,
    const unsigned short* __restrict__ Kb,
    const unsigned short* __restrict__ Vt,
    float* __restrict__ OP, float* __restrict__ ML)
{
    const int bb = blockIdx.x;
    // tile pair m: tiles 2m (j=m+1 chunks) and 2m+1 (j=m+1); group base m(m+1)
    int m = 0;
    while ((m + 1) * (m + 2) <= bb) ++m;             // <=31 scalar iters
    const int r_ = bb - m * (m + 1);
    const int t  = (r_ < m + 1) ? 2 * m : 2 * m + 1;
    const int c  = (r_ < m + 1) ? r_ : r_ - (m + 1);
    const int kstart = 128 * c;
    const int kend   = min(128 * (c + 1), 64 * t + 64);

    const int tid = threadIdx.x, w = tid >> 6, lane = tid & 63;
    const int li = lane & 15, gl = lane >> 4;
    const int q0 = 64 * t + 32 * w;

    __shared__ unsigned short Ks[2][32 * DK];   // [key][dk] swizzled, 8 KB
    __shared__ unsigned short Vs[2][DK * 32];   // [dv][key] swizzled, 8 KB
    __shared__ unsigned short Pl[2][32][40];    // per-wave P bounce (padded)

    // ---- Q fragments (A-layout rows = q)
    short8 aq[2][4];
    #pragma unroll
    for (int qs = 0; qs < 2; ++qs)
        #pragma unroll
        for (int s = 0; s < 4; ++s)
            aq[qs][s] = *(const short8*)
                &Qb[(size_t)(q0 + 16 * qs + li) * DK + 32 * s + 8 * gl];

    f32x4 accv[2][8];
    #pragma unroll
    for (int qs = 0; qs < 2; ++qs)
        #pragma unroll
        for (int n = 0; n < 8; ++n)
            #pragma unroll
            for (int r = 0; r < 4; ++r) accv[qs][n][r] = 0.f;

    float mr[2] = {-1e30f, -1e30f}, lr[2] = {0.f, 0.f};
    const float scale = 0.08838834764831845f;  // 1/sqrt(128)

    // ---- staging: 512 16B-chunks per K and V tile; thread does 4 of each.
    // K: chunk ch: key=ch>>4, ck=ch&15 -> LDS elem key*128 + (ck^(key&7))*8
    // V: chunk ch: dv=ch>>2,  ck=ch&3  -> LDS elem dv*32  + (ck^((dv>>1)&3))*8
    {
        #pragma unroll
        for (int i = 0; i < 4; ++i) {
            const int ch = tid + 128 * i;
            const int key = ch >> 4, ckk = ch & 15;
            const int dv  = ch >> 2, ckv = ch & 3;
            const short8 sk = *(const short8*)
                &Kb[(size_t)(kstart + key) * DK + ckk * 8];
            const short8 sv = *(const short8*)
                &Vt[(size_t)dv * S + kstart + ckv * 8];
            *(short8*)&Ks[0][key * DK + ((ckk ^ (key & 7)) * 8)] = sk;
            *(short8*)&Vs[0][dv * 32 + ((ckv ^ ((dv >> 1) & 3)) * 8)] = sv;
        }
    }
    __syncthreads();

    int cur = 0;
    for (int kb = kstart; kb < kend; kb += 32) {
        const bool pf = (kb + 32 < kend);

        // ---- issue next tile's global loads NOW (land during compute)
        short8 stK[4], stV[4];
        if (pf) {
            const int kn = kb + 32;
            #pragma unroll
            for (int i = 0; i < 4; ++i) {
                const int ch = tid + 128 * i;
                stK[i] = *(const short8*)
                    &Kb[(size_t)(kn + (ch >> 4)) * DK + (ch & 15) * 8];
                stV[i] = *(const short8*)
                    &Vt[(size_t)(ch >> 2) * S + kn + (ch & 3) * 8];
            }
        }

        // ---- K/V fragments from LDS (swizzled addresses, conflict-free)
        const unsigned short* Ksb = &Ks[cur][0];
        const unsigned short* Vsb = &Vs[cur][0];
        short8 kf[2][4], vf[8];
        #pragma unroll
        for (int kt = 0; kt < 2; ++kt)
            #pragma unroll
            for (int s = 0; s < 4; ++s)
                kf[kt][s] = *(const short8*)
                    &Ksb[(16 * kt + li) * DK + (((4 * s + gl) ^ (li & 7)) * 8)];
        #pragma unroll
        for (int n = 0; n < 8; ++n)
            vf[n] = *(const short8*)
                &Vsb[(16 * n + li) * 32 + ((gl ^ ((li >> 1) & 3)) * 8)];

        // ---- QK^T swapped: D = S^T [key][q], q = li (per-lane column)
        f32x4 sc[2][2];
        #pragma unroll
        for (int qs = 0; qs < 2; ++qs)
            #pragma unroll
            for (int kt = 0; kt < 2; ++kt)
                #pragma unroll
                for (int r = 0; r < 4; ++r) sc[qs][kt][r] = 0.f;
        __builtin_amdgcn_s_setprio(1);
        #pragma unroll
        for (int qs = 0; qs < 2; ++qs)
            #pragma unroll
            for (int kt = 0; kt < 2; ++kt)
                #pragma unroll
                for (int s = 0; s < 4; ++s)
                    sc[qs][kt] = __builtin_amdgcn_mfma_f32_16x16x32_bf16(
                        kf[kt][s], aq[qs][s], sc[qs][kt], 0, 0, 0);
        __builtin_amdgcn_s_setprio(0);

        // ---- scale + causal mask: key = kb+16kt+4gl+r, q = q0+16qs+li
        #pragma unroll
        for (int qs = 0; qs < 2; ++qs) {
            const int q = q0 + 16 * qs + li;
            #pragma unroll
            for (int kt = 0; kt < 2; ++kt)
                #pragma unroll
                for (int r = 0; r < 4; ++r) {
                    const int key = kb + 16 * kt + 4 * gl + r;
                    sc[qs][kt][r] = (key > q) ? -1e30f : sc[qs][kt][r] * scale;
                }
        }

        // ---- per-q tile max: 7 in-lane fmax + 2 shfl
        float tm[2];
        #pragma unroll
        for (int qs = 0; qs < 2; ++qs) {
            float v = fmaxf(fmaxf(fmaxf(sc[qs][0][0], sc[qs][0][1]),
                                  fmaxf(sc[qs][0][2], sc[qs][0][3])),
                            fmaxf(fmaxf(sc[qs][1][0], sc[qs][1][1]),
                                  fmaxf(sc[qs][1][2], sc[qs][1][3])));
            v = fmaxf(v, __shfl_xor(v, 16));
            v = fmaxf(v, __shfl_xor(v, 32));
            tm[qs] = v;
        }

        // ---- defer-max rescale (THR=6), wave-uniform branch
        const int need = (tm[0] > mr[0] + 6.f) | (tm[1] > mr[1] + 6.f);
        if (__any(need)) {
            float corr[2];
            #pragma unroll
            for (int qs = 0; qs < 2; ++qs) {
                const float mnew = fmaxf(mr[qs], tm[qs]);
                corr[qs] = __expf(mr[qs] - mnew);
                lr[qs] *= corr[qs];
                mr[qs]  = mnew;
            }
            #pragma unroll
            for (int qs = 0; qs < 2; ++qs)
                #pragma unroll
                for (int r = 0; r < 4; ++r) {
                    const float cr = __shfl(corr[qs], 4 * gl + r); // q=4gl+r
                    #pragma unroll
                    for (int n = 0; n < 8; ++n) accv[qs][n][r] *= cr;
                }
        }

        // ---- exp + row-sum (in-lane 8 + 2 shfl)
        #pragma unroll
        for (int qs = 0; qs < 2; ++qs) {
            float ps = 0.f;
            #pragma unroll
            for (int kt = 0; kt < 2; ++kt)
                #pragma unroll
                for (int r = 0; r < 4; ++r) {
                    const float p = __expf(sc[qs][kt][r] - mr[qs]);
                    sc[qs][kt][r] = p;
                    ps += p;
                }
            ps += __shfl_xor(ps, 16);
            ps += __shfl_xor(ps, 32);
            lr[qs] += ps;
        }

        // ---- P[q=li][k] -> per-wave LDS (8B packs), reread as A-frag
        #pragma unroll
        for (int qs = 0; qs < 2; ++qs)
            #pragma unroll
            for (int kt = 0; kt < 2; ++kt) {
                u16x4 wv;
                #pragma unroll
                for (int r = 0; r < 4; ++r) wv[r] = f2bf(sc[qs][kt][r]);
                *(u16x4*)&Pl[w][16 * qs + li][16 * kt + 4 * gl] = wv;
            }
        const short8 pa0 = *(const short8*)&Pl[w][li][8 * gl];
        const short8 pa1 = *(const short8*)&Pl[w][16 + li][8 * gl];

        // ---- PV
        __builtin_amdgcn_s_setprio(1);
        #pragma unroll
        for (int n = 0; n < 8; ++n) {
            accv[0][n] = __builtin_amdgcn_mfma_f32_16x16x32_bf16(pa0, vf[n], accv[0][n], 0, 0, 0);
            accv[1][n] = __builtin_amdgcn_mfma_f32_16x16x32_bf16(pa1, vf[n], accv[1][n], 0, 0, 0);
        }
        __builtin_amdgcn_s_setprio(0);

        // ---- write next tile to LDS (swizzled), one barrier, swap
        if (pf) {
            #pragma unroll
            for (int i = 0; i < 4; ++i) {
                const int ch = tid + 128 * i;
                const int key = ch >> 4, ckk = ch & 15;
                const int dv  = ch >> 2, ckv = ch & 3;
                *(short8*)&Ks[cur ^ 1][key * DK + ((ckk ^ (key & 7)) * 8)] = stK[i];
                *(short8*)&Vs[cur ^ 1][dv * 32 + ((ckv ^ ((dv >> 1) & 3)) * 8)] = stV[i];
            }
            __syncthreads();
        }
        cur ^= 1;
    }

    // ---- store unnormalized partial O + per-lane (m,l), nontemporal
    #pragma unroll
    for (int qs = 0; qs < 2; ++qs)
        #pragma unroll
        for (int n = 0; n < 8; ++n)
            #pragma unroll
            for (int r = 0; r < 4; ++r)
                __builtin_nontemporal_store(accv[qs][n][r],
                    &OP[((size_t)bb * 64 + 32 * w + 16 * qs + 4 * gl + r) * DK
                        + 16 * n + li]);
    if (gl == 0) {
        #pragma unroll
        for (int qs = 0; qs < 2; ++qs) {
            ML[((size_t)bb * 64 + 32 * w + 16 * qs + li) * 2 + 0] = mr[qs];
            ML[((size_t)bb * 64 + 32 * w + 16 * qs + li) * 2 + 1] = lr[qs];
        }
    }
}

// ---------------------------------------------------------------------------
// Merge <=32 causal-split partials per q-row. grid = S blocks, block = DK.
// Row tile T = row>>6 (64-row tiles): m = T>>1, j = m+1 chunks,
// base = (T even) ? m(m+1) : (m+1)^2.
// ---------------------------------------------------------------------------
__global__ __launch_bounds__(DK) void merge_kernel(
    const float* __restrict__ OP, const float* __restrict__ ML,
    float* __restrict__ out)
{
    const int row = blockIdx.x, dv = threadIdx.x;
    const int T  = row >> 6, rl = row & 63;
    const int m  = T >> 1;
    const int j  = m + 1;
    const int base = (T & 1) ? (m + 1) * (m + 1) : m * (m + 1);

    float M = -1e30f;
    for (int c = 0; c < j; ++c)
        M = fmaxf(M, ((const float2*)ML)[(size_t)(base + c) * 64 + rl].x);
    float L = 0.f, o = 0.f;
    #pragma unroll 2
    for (int c = 0; c < j; ++c) {
        const float2 ml = ((const float2*)ML)[(size_t)(base + c) * 64 + rl];
        const float wgt = __expf(ml.x - M);
        L += ml.y * wgt;
        o += wgt * __builtin_nontemporal_load(
                 &OP[((size_t)(base + c) * 64 + rl) * DK + dv]);
    }
    out[(size_t)row * DK + dv] = o / L;
}

// ---------------------------------------------------------------------------
extern "C" void kernel_launch(void* const* d_in, const int* in_sizes, int n_in,
                              void* d_out, int out_size, void* d_ws, size_t ws_size,
                              hipStream_t stream)
{
    (void)in_sizes; (void)n_in; (void)out_size; (void)ws_size;
    const float* X  = (const float*)d_in[0];
    const float* Wq = (const float*)d_in[1];
    const float* bq = (const float*)d_in[2];
    const float* Wk = (const float*)d_in[3];
    const float* bk = (const float*)d_in[4];
    const float* Wv = (const float*)d_in[5];
    const float* bv = (const float*)d_in[6];
    float* out = (float*)d_out;

    // ws (~40 MB): Wb | Qb | Kb | Vt | union{ Xb (dead after proj),
    //                                         OP [1056][64][DK] f32 } | ML
    unsigned short* Wb = (unsigned short*)d_ws;
    unsigned short* Qb = Wb + (size_t)3 * DK * DMODEL;
    unsigned short* Kb = Qb + (size_t)S * DK;
    unsigned short* Vt = Kb + (size_t)S * DK;
    unsigned short* Xb = Vt + (size_t)S * DK;
    float* OP = (float*)Xb;                      // aliases Xb (sequential use)
    float* ML = OP + (size_t)NB_ATTN * 64 * DK;

    cvt_kernel<<<2240, 256, 0, stream>>>(X, Wq, Wk, Wv, Xb, Wb);
    proj_gemm<<<dim3(S / 16, 3, 2), 128, 0, stream>>>(
        Xb, Wb, bq, bk, bv, Qb, Kb, Vt);
    attn_mfma<<<NB_ATTN, 128, 0, stream>>>(Qb, Kb, Vt, OP, ML);
    merge_kernel<<<S, DK, 0, stream>>>(OP, ML, out);
}